// Round 17
// baseline (39.939 us; speedup 1.0000x reference)
//
#include <hip/hip_runtime.h>
#include <math.h>

#define BB 2
#define NN 1024
#define DD 48
#define DH 12
#define NSLOT 8     // j-splitgroups of 4 waves; 32 j-splits total

// force_mag(dist, mi, mj) lookup, packed: table4[(di*NM+mi)*NM+mj] =
// {v(mi,mj), v(mi,mj+1), v(mi+1,mj), v(mi+1,mj+1)}  -> 2 gathers per pair.
#define ND 64
#define NM 8
#define D_LO 4.0f
#define D_HI 16.0f
#define DSTEP ((D_HI - D_LO) / (float)(ND - 1))
#define DINV  ((float)(ND - 1) / (D_HI - D_LO))
#define M_LO 0.25f
#define M_HI 1.45f
#define MSTEP ((M_HI - M_LO) / (float)(NM - 1))
#define MINV  ((float)(NM - 1) / (M_HI - M_LO))

__device__ __forceinline__ float gelu_exact(float x) {
    return 0.5f * x * (1.0f + erff(x * 0.70710678118654752f));
}
__device__ __forceinline__ float gelu_fast(float x) {
    float u = x * x;
    float p = __builtin_fmaf(0.044715f * x, u, x);
    float z = 1.5957691216057308f * p;
    float e = __expf(-z);
    return x * __builtin_amdgcn_rcpf(1.0f + e);
}
__device__ __forceinline__ float softplus_f(float x) {
    return (x > 20.0f) ? x : log1pf(expf(x));
}

// ======== prep ========
// blocks [0,64): table4 (64 entries/block = one di-level)
// blocks [64,96): per-particle nm4 {norm2, massT, dt^2/(m+.1), dt/(m+.1)}
//                 + write integration BASE terms into out (replay-safe:
//                 fully overwritten each call, BEFORE force's atomic adds).
__global__ __launch_bounds__(256) void prep_kernel(
    const float* __restrict__ pos, const float* __restrict__ vel,
    const float* __restrict__ m_w1, const float* __restrict__ m_b1,
    const float* __restrict__ m_w2, const float* __restrict__ m_b2,
    const float* __restrict__ f_w1, const float* __restrict__ f_b1,
    const float* __restrict__ f_w2, const float* __restrict__ f_b2,
    const float* __restrict__ f_w3, const float* __restrict__ f_b3,
    const float* __restrict__ damping_p, const float* __restrict__ dt_p,
    float4* __restrict__ nm4, float4* __restrict__ table4,
    float* __restrict__ out)
{
    int tid = threadIdx.x;
    int el = tid >> 2, r = tid & 3;        // quad-local: entry-in-block, k/d-slice
    if (blockIdx.x < 64) {
        __shared__ float sFm[64];
        int e = blockIdx.x * 64 + el;      // 0..4095: e = (di*8 + mi)*8 + mj
        int mj = e & (NM - 1);
        int mi = (e >> 3) & (NM - 1);
        int di = e >> 6;
        float dist = D_LO + di * DSTEP;
        float vmi = M_LO + mi * MSTEP, vmj = M_LO + mj * MSTEP;

        float t[12];
        {
            const float4* b2 = (const float4*)(f_b2 + 12 * r);
            float4 a = b2[0], b = b2[1], c = b2[2];
            t[0]=a.x; t[1]=a.y; t[2]=a.z; t[3]=a.w;
            t[4]=b.x; t[5]=b.y; t[6]=b.z; t[7]=b.w;
            t[8]=c.x; t[9]=c.y; t[10]=c.z; t[11]=c.w;
        }
        #pragma unroll 4
        for (int c = 0; c < DD; ++c) {
            float h = gelu_fast(f_b1[c] + dist * f_w1[c] + vmi * f_w1[DD + c]
                                + vmj * f_w1[2 * DD + c]);
            const float4* wr = (const float4*)(f_w2 + c * DD + 12 * r);
            float4 w0 = wr[0], w1 = wr[1], w2v = wr[2];
            t[0] = fmaf(h, w0.x, t[0]);  t[1] = fmaf(h, w0.y, t[1]);
            t[2] = fmaf(h, w0.z, t[2]);  t[3] = fmaf(h, w0.w, t[3]);
            t[4] = fmaf(h, w1.x, t[4]);  t[5] = fmaf(h, w1.y, t[5]);
            t[6] = fmaf(h, w1.z, t[6]);  t[7] = fmaf(h, w1.w, t[7]);
            t[8] = fmaf(h, w2v.x, t[8]); t[9] = fmaf(h, w2v.y, t[9]);
            t[10] = fmaf(h, w2v.z, t[10]); t[11] = fmaf(h, w2v.w, t[11]);
        }
        float fm;
        {
            const float4* w3p = (const float4*)(f_w3 + 12 * r);
            float4 a = w3p[0], b = w3p[1], c = w3p[2];
            fm  = gelu_fast(t[0]) * a.x + gelu_fast(t[1]) * a.y
                + gelu_fast(t[2]) * a.z + gelu_fast(t[3]) * a.w
                + gelu_fast(t[4]) * b.x + gelu_fast(t[5]) * b.y
                + gelu_fast(t[6]) * b.z + gelu_fast(t[7]) * b.w
                + gelu_fast(t[8]) * c.x + gelu_fast(t[9]) * c.y
                + gelu_fast(t[10]) * c.z + gelu_fast(t[11]) * c.w;
        }
        fm += __shfl_xor(fm, 1);
        fm += __shfl_xor(fm, 2);
        fm += f_b3[0];
        if (r == 0) sFm[el] = fm;
        __syncthreads();
        if (tid < 64) {
            int mjj = tid & 7, mii = (tid >> 3) & 7;
            float v00 = sFm[tid];
            float v01 = (mjj == 7) ? v00 : sFm[tid + 1];
            float v10 = (mii == 7) ? v00 : sFm[tid + 8];
            float v11 = (mii == 7) ? v01 : ((mjj == 7) ? v10 : sFm[tid + 9]);
            // mi=7 / mj=7 entries never dereferenced (massT clamped <= NM-1-eps)
            table4[blockIdx.x * 64 + tid] = make_float4(v00, v01, v10, v11);
        }
    } else {
        int p = (blockIdx.x - 64) * 64 + el;   // 0..2047
        const float4* xp = (const float4*)(pos + (size_t)p * DD + 12 * r);
        float4 x0 = xp[0], x1 = xp[1], x2 = xp[2];
        const float4* vp = (const float4*)(vel + (size_t)p * DD + 12 * r);
        float4 v0 = vp[0], v1 = vp[1], v2 = vp[2];
        float damping = damping_p[0], dt = dt_p[0];

        // integration bases: vel_base = damping*v ; pos_base = x + dt*vel_base
        float4 bv0, bv1, bv2, bp0, bp1, bp2;
        bv0.x = damping*v0.x; bv0.y = damping*v0.y; bv0.z = damping*v0.z; bv0.w = damping*v0.w;
        bv1.x = damping*v1.x; bv1.y = damping*v1.y; bv1.z = damping*v1.z; bv1.w = damping*v1.w;
        bv2.x = damping*v2.x; bv2.y = damping*v2.y; bv2.z = damping*v2.z; bv2.w = damping*v2.w;
        bp0.x = fmaf(dt, bv0.x, x0.x); bp0.y = fmaf(dt, bv0.y, x0.y);
        bp0.z = fmaf(dt, bv0.z, x0.z); bp0.w = fmaf(dt, bv0.w, x0.w);
        bp1.x = fmaf(dt, bv1.x, x1.x); bp1.y = fmaf(dt, bv1.y, x1.y);
        bp1.z = fmaf(dt, bv1.z, x1.z); bp1.w = fmaf(dt, bv1.w, x1.w);
        bp2.x = fmaf(dt, bv2.x, x2.x); bp2.y = fmaf(dt, bv2.y, x2.y);
        bp2.z = fmaf(dt, bv2.z, x2.z); bp2.w = fmaf(dt, bv2.w, x2.w);
        const int NTOT = BB * NN * DD;
        size_t eb = (size_t)p * DD + 12 * r;
        *(float4*)&out[eb + 0] = bp0; *(float4*)&out[eb + 4] = bp1; *(float4*)&out[eb + 8] = bp2;
        *(float4*)&out[NTOT + eb + 0] = bv0; *(float4*)&out[NTOT + eb + 4] = bv1;
        *(float4*)&out[NTOT + eb + 8] = bv2;

        float xs[12];
        xs[0]=x0.x; xs[1]=x0.y; xs[2]=x0.z; xs[3]=x0.w;
        xs[4]=x1.x; xs[5]=x1.y; xs[6]=x1.z; xs[7]=x1.w;
        xs[8]=x2.x; xs[9]=x2.y; xs[10]=x2.z; xs[11]=x2.w;
        float n2 = 0.f;
        #pragma unroll
        for (int j = 0; j < 12; ++j) n2 = fmaf(xs[j], xs[j], n2);
        n2 += __shfl_xor(n2, 1);
        n2 += __shfl_xor(n2, 2);

        float t[12];
        #pragma unroll
        for (int k = 0; k < 12; ++k) t[k] = 0.f;
        #pragma unroll
        for (int j = 0; j < 12; ++j) {
            const float4* wr = (const float4*)(m_w1 + (size_t)(12 * r + j) * DH);
            float4 a = wr[0], b = wr[1], c = wr[2];
            float xj = xs[j];
            t[0] = fmaf(xj, a.x, t[0]);  t[1] = fmaf(xj, a.y, t[1]);
            t[2] = fmaf(xj, a.z, t[2]);  t[3] = fmaf(xj, a.w, t[3]);
            t[4] = fmaf(xj, b.x, t[4]);  t[5] = fmaf(xj, b.y, t[5]);
            t[6] = fmaf(xj, b.z, t[6]);  t[7] = fmaf(xj, b.w, t[7]);
            t[8] = fmaf(xj, c.x, t[8]);  t[9] = fmaf(xj, c.y, t[9]);
            t[10] = fmaf(xj, c.z, t[10]); t[11] = fmaf(xj, c.w, t[11]);
        }
        #pragma unroll
        for (int k = 0; k < 12; ++k) {
            t[k] += __shfl_xor(t[k], 1);
            t[k] += __shfl_xor(t[k], 2);
        }
        float m2 = m_b2[0];
        #pragma unroll
        for (int k = 0; k < 12; ++k)
            m2 += gelu_exact(t[k] + m_b1[k]) * m_w2[k];
        if (r == 0) {
            float m = softplus_f(m2);
            float inv = 1.0f / (m + 0.1f);
            float mt = fminf(fmaxf((m - M_LO) * MINV, 0.f), (float)(NM - 1) - 1e-3f);
            nm4[p] = make_float4(n2, mt, dt * dt * inv, dt * inv);
        }
    }
}

// ======== force + linear-integrate fold (atomic adds into out) ========
__global__ __launch_bounds__(256) void force_kernel(
    const float* __restrict__ pos, const float4* __restrict__ nm4,
    const float4* __restrict__ table4, float* __restrict__ out)
{
    int bid = blockIdx.x;                 // 1024 blocks
    int b = bid & 1;
    int r = bid >> 1;                     // 0..511
    int s = 63 - (r >> 3);                // heavy strips dispatched first
    int g = r & 7;                        // splitgroup
    int tid = threadIdx.x;
    int wid = tid >> 6;
    int lane = tid & 63;
    int li = lane >> 2, q = lane & 3;
    int k = g * 4 + wid;                  // j-split 0..31
    int i0 = s * 16;
    int gi = i0 + li;
    int jmax = i0 + 15;

    const float4* prI = (const float4*)(pos + (size_t)(b * NN + gi) * DD) + 3 * q;
    float4 pi0 = prI[0], pi1 = prI[1], pi2 = prI[2];
    float4 nmI = nm4[b * NN + gi];
    int mi0 = (int)nmI.y; float fi = nmI.y - mi0; int miN = mi0 * NM;

    float SA = 0.f, SB = 0.f;
    float4 VA0 = make_float4(0.f,0.f,0.f,0.f), VA1 = VA0, VA2 = VA0;
    float4 VB0 = VA0, VB1 = VA0, VB2 = VA0;

    for (int j = k; j <= jmax; j += 64) {
        int jB = j + 32;
        bool hasB = (jB <= jmax);
        const float4* sjA = (const float4*)(pos + (size_t)(b * NN + j) * DD) + 3 * q;
        float4 pA0 = sjA[0], pA1 = sjA[1], pA2 = sjA[2];
        float4 nmA = nm4[b * NN + j];
        float4 pB0, pB1, pB2, nmB;
        if (hasB) {
            const float4* sjB = (const float4*)(pos + (size_t)(b * NN + jB) * DD) + 3 * q;
            pB0 = sjB[0]; pB1 = sjB[1]; pB2 = sjB[2];
            nmB = nm4[b * NN + jB];
        }

        float dpA = pi0.x * pA0.x;
        dpA = fmaf(pi0.y, pA0.y, dpA); dpA = fmaf(pi0.z, pA0.z, dpA); dpA = fmaf(pi0.w, pA0.w, dpA);
        dpA = fmaf(pi1.x, pA1.x, dpA); dpA = fmaf(pi1.y, pA1.y, dpA);
        dpA = fmaf(pi1.z, pA1.z, dpA); dpA = fmaf(pi1.w, pA1.w, dpA);
        dpA = fmaf(pi2.x, pA2.x, dpA); dpA = fmaf(pi2.y, pA2.y, dpA);
        dpA = fmaf(pi2.z, pA2.z, dpA); dpA = fmaf(pi2.w, pA2.w, dpA);
        dpA += __shfl_xor(dpA, 1);
        dpA += __shfl_xor(dpA, 2);
        float dpB = 0.f;
        if (hasB) {
            dpB = pi0.x * pB0.x;
            dpB = fmaf(pi0.y, pB0.y, dpB); dpB = fmaf(pi0.z, pB0.z, dpB); dpB = fmaf(pi0.w, pB0.w, dpB);
            dpB = fmaf(pi1.x, pB1.x, dpB); dpB = fmaf(pi1.y, pB1.y, dpB);
            dpB = fmaf(pi1.z, pB1.z, dpB); dpB = fmaf(pi1.w, pB1.w, dpB);
            dpB = fmaf(pi2.x, pB2.x, dpB); dpB = fmaf(pi2.y, pB2.y, dpB);
            dpB = fmaf(pi2.z, pB2.z, dpB); dpB = fmaf(pi2.w, pB2.w, dpB);
        }
        dpB += __shfl_xor(dpB, 1);
        dpB += __shfl_xor(dpB, 2);

        {   // ---- lookup A (2 packed gathers) ----
            float s2 = fmaxf(nmI.x + nmA.x - 2.f * dpA, 0.f);
            float dist = fmaxf(sqrtf(s2), 0.01f);
            float td = fminf(fmaxf((dist - D_LO) * DINV, 0.f), (float)(ND - 1) - 1e-3f);
            int di0 = (int)td; float fd = td - di0;
            int nj0 = (int)nmA.y; float fj = nmA.y - nj0;
            int idx = di0 * (NM * NM) + miN + nj0;
            float4 q0 = table4[idx];
            float4 q1 = table4[idx + NM * NM];
            float a0 = q0.x + fj * (q0.y - q0.x);
            float a1 = q0.z + fj * (q0.w - q0.z);
            float y0 = a0 + fi * (a1 - a0);
            float b0 = q1.x + fj * (q1.y - q1.x);
            float b1 = q1.z + fj * (q1.w - q1.z);
            float y1 = b0 + fi * (b1 - b0);
            float fmv = y0 + fd * (y1 - y0);
            float rr = (j <= gi) ? fmv * __builtin_amdgcn_rcpf(dist) : 0.f;
            SA += rr;
            VA0.x = fmaf(rr, pA0.x, VA0.x); VA0.y = fmaf(rr, pA0.y, VA0.y);
            VA0.z = fmaf(rr, pA0.z, VA0.z); VA0.w = fmaf(rr, pA0.w, VA0.w);
            VA1.x = fmaf(rr, pA1.x, VA1.x); VA1.y = fmaf(rr, pA1.y, VA1.y);
            VA1.z = fmaf(rr, pA1.z, VA1.z); VA1.w = fmaf(rr, pA1.w, VA1.w);
            VA2.x = fmaf(rr, pA2.x, VA2.x); VA2.y = fmaf(rr, pA2.y, VA2.y);
            VA2.z = fmaf(rr, pA2.z, VA2.z); VA2.w = fmaf(rr, pA2.w, VA2.w);
        }
        if (hasB) {  // ---- lookup B ----
            float s2 = fmaxf(nmI.x + nmB.x - 2.f * dpB, 0.f);
            float dist = fmaxf(sqrtf(s2), 0.01f);
            float td = fminf(fmaxf((dist - D_LO) * DINV, 0.f), (float)(ND - 1) - 1e-3f);
            int di0 = (int)td; float fd = td - di0;
            int nj0 = (int)nmB.y; float fj = nmB.y - nj0;
            int idx = di0 * (NM * NM) + miN + nj0;
            float4 q0 = table4[idx];
            float4 q1 = table4[idx + NM * NM];
            float a0 = q0.x + fj * (q0.y - q0.x);
            float a1 = q0.z + fj * (q0.w - q0.z);
            float y0 = a0 + fi * (a1 - a0);
            float b0 = q1.x + fj * (q1.y - q1.x);
            float b1 = q1.z + fj * (q1.w - q1.z);
            float y1 = b0 + fi * (b1 - b0);
            float fmv = y0 + fd * (y1 - y0);
            float rr = (jB <= gi) ? fmv * __builtin_amdgcn_rcpf(dist) : 0.f;
            SB += rr;
            VB0.x = fmaf(rr, pB0.x, VB0.x); VB0.y = fmaf(rr, pB0.y, VB0.y);
            VB0.z = fmaf(rr, pB0.z, VB0.z); VB0.w = fmaf(rr, pB0.w, VB0.w);
            VB1.x = fmaf(rr, pB1.x, VB1.x); VB1.y = fmaf(rr, pB1.y, VB1.y);
            VB1.z = fmaf(rr, pB1.z, VB1.z); VB1.w = fmaf(rr, pB1.w, VB1.w);
            VB2.x = fmaf(rr, pB2.x, VB2.x); VB2.y = fmaf(rr, pB2.y, VB2.y);
            VB2.z = fmaf(rr, pB2.z, VB2.z); VB2.w = fmaf(rr, pB2.w, VB2.w);
        }
    }
    float S = SA + SB;
    float4 V0, V1, V2;
    V0.x = VA0.x + VB0.x; V0.y = VA0.y + VB0.y; V0.z = VA0.z + VB0.z; V0.w = VA0.w + VB0.w;
    V1.x = VA1.x + VB1.x; V1.y = VA1.y + VB1.y; V1.z = VA1.z + VB1.z; V1.w = VA1.w + VB1.w;
    V2.x = VA2.x + VB2.x; V2.y = VA2.y + VB2.y; V2.z = VA2.z + VB2.z; V2.w = VA2.w + VB2.w;

    __shared__ __align__(16) float red[4][16][48];
    float4 f0, f1, f2;
    f0.x = pi0.x * S - V0.x; f0.y = pi0.y * S - V0.y;
    f0.z = pi0.z * S - V0.z; f0.w = pi0.w * S - V0.w;
    f1.x = pi1.x * S - V1.x; f1.y = pi1.y * S - V1.y;
    f1.z = pi1.z * S - V1.z; f1.w = pi1.w * S - V1.w;
    f2.x = pi2.x * S - V2.x; f2.y = pi2.y * S - V2.y;
    f2.z = pi2.z * S - V2.z; f2.w = pi2.w * S - V2.w;
    float4* rp = (float4*)&red[wid][li][12 * q];
    rp[0] = f0; rp[1] = f1; rp[2] = f2;
    __syncthreads();

    // block-reduce 4 waves, then ATOMIC-fold the linear integrate into out:
    // out_pos += dt^2/(m+.1) * f ; out_vel += dt/(m+.1) * f  (bases from prep)
    if (tid < 192) {
        int i = tid / 12, c4 = tid - (tid / 12) * 12;
        float4 acc = *(const float4*)&red[0][i][4 * c4];
        #pragma unroll
        for (int w = 1; w < 4; ++w) {
            float4 v = *(const float4*)&red[w][i][4 * c4];
            acc.x += v.x; acc.y += v.y; acc.z += v.z; acc.w += v.w;
        }
        int row = b * NN + i0 + i;
        float4 sc = nm4[row];             // .z = dt^2*inv, .w = dt*inv
        const int NTOT = BB * NN * DD;
        size_t e = (size_t)row * DD + 4 * c4;
        float* op = out + e;
        float* ov = out + NTOT + e;
        atomicAdd(&op[0], sc.z * acc.x);
        atomicAdd(&op[1], sc.z * acc.y);
        atomicAdd(&op[2], sc.z * acc.z);
        atomicAdd(&op[3], sc.z * acc.w);
        atomicAdd(&ov[0], sc.w * acc.x);
        atomicAdd(&ov[1], sc.w * acc.y);
        atomicAdd(&ov[2], sc.w * acc.z);
        atomicAdd(&ov[3], sc.w * acc.w);
    }
}

extern "C" void kernel_launch(void* const* d_in, const int* in_sizes, int n_in,
                              void* d_out, int out_size, void* d_ws, size_t ws_size,
                              hipStream_t stream) {
    const float* pos  = (const float*)d_in[0];
    const float* vel  = (const float*)d_in[1];
    const float* m_w1 = (const float*)d_in[2];
    const float* m_b1 = (const float*)d_in[3];
    const float* m_w2 = (const float*)d_in[4];
    const float* m_b2 = (const float*)d_in[5];
    const float* f_w1 = (const float*)d_in[6];
    const float* f_b1 = (const float*)d_in[7];
    const float* f_w2 = (const float*)d_in[8];
    const float* f_b2 = (const float*)d_in[9];
    const float* f_w3 = (const float*)d_in[10];
    const float* f_b3 = (const float*)d_in[11];
    const float* damping = (const float*)d_in[12];
    const float* dt   = (const float*)d_in[13];

    float4* nm4_ws    = (float4*)d_ws;                     // 2048 float4
    float4* table4_ws = nm4_ws + BB * NN;                  // 4096 float4

    prep_kernel<<<96, 256, 0, stream>>>(pos, vel, m_w1, m_b1, m_w2, m_b2,
                                        f_w1, f_b1, f_w2, f_b2, f_w3, f_b3,
                                        damping, dt, nm4_ws, table4_ws,
                                        (float*)d_out);

    force_kernel<<<BB * 64 * NSLOT, 256, 0, stream>>>(pos, nm4_ws, table4_ws,
                                                      (float*)d_out);
}

// Round 18
// 30.973 us; speedup vs baseline: 1.2895x; 1.2895x over previous
//
#include <hip/hip_runtime.h>
#include <math.h>

#define BB 2
#define NN 1024
#define DD 48
#define DH 12
#define NSLOT 8     // partial slots (splitgroups of 4 waves); 32 j-splits total

// force_mag(dist, mi, mj) lookup, packed: table4[(di*NM+mi)*NM+mj] =
// {v(mi,mj), v(mi,mj+1), v(mi+1,mj), v(mi+1,mj+1)}  -> 2 gathers per pair.
#define ND 64
#define NM 8
#define D_LO 4.0f
#define D_HI 16.0f
#define DSTEP ((D_HI - D_LO) / (float)(ND - 1))
#define DINV  ((float)(ND - 1) / (D_HI - D_LO))
#define M_LO 0.25f
#define M_HI 1.45f
#define MSTEP ((M_HI - M_LO) / (float)(NM - 1))
#define MINV  ((float)(NM - 1) / (M_HI - M_LO))

__device__ __forceinline__ float gelu_exact(float x) {
    return 0.5f * x * (1.0f + erff(x * 0.70710678118654752f));
}
__device__ __forceinline__ float gelu_fast(float x) {
    float u = x * x;
    float p = __builtin_fmaf(0.044715f * x, u, x);
    float z = 1.5957691216057308f * p;
    float e = __expf(-z);
    return x * __builtin_amdgcn_rcpf(1.0f + e);
}
__device__ __forceinline__ float softplus_f(float x) {
    return (x > 20.0f) ? x : log1pf(expf(x));
}

// ======== prep: quad-of-lanes per table entry / per particle ========
// blocks [0,64): table4 (64 entries/block = one di-level); [64,96): mass+nm2
__global__ __launch_bounds__(256) void prep_kernel(
    const float* __restrict__ pos,
    const float* __restrict__ m_w1, const float* __restrict__ m_b1,
    const float* __restrict__ m_w2, const float* __restrict__ m_b2,
    const float* __restrict__ f_w1, const float* __restrict__ f_b1,
    const float* __restrict__ f_w2, const float* __restrict__ f_b2,
    const float* __restrict__ f_w3, const float* __restrict__ f_b3,
    float* __restrict__ mass_out, float2* __restrict__ nm2,
    float4* __restrict__ table4)
{
    int tid = threadIdx.x;
    int el = tid >> 2, r = tid & 3;        // quad-local: entry-in-block, k/d-slice
    if (blockIdx.x < 64) {
        __shared__ float sFm[64];
        int e = blockIdx.x * 64 + el;      // 0..4095: e = (di*8 + mi)*8 + mj
        int mj = e & (NM - 1);
        int mi = (e >> 3) & (NM - 1);
        int di = e >> 6;
        float dist = D_LO + di * DSTEP;
        float vmi = M_LO + mi * MSTEP, vmj = M_LO + mj * MSTEP;

        float t[12];
        {
            const float4* b2 = (const float4*)(f_b2 + 12 * r);
            float4 a = b2[0], b = b2[1], c = b2[2];
            t[0]=a.x; t[1]=a.y; t[2]=a.z; t[3]=a.w;
            t[4]=b.x; t[5]=b.y; t[6]=b.z; t[7]=b.w;
            t[8]=c.x; t[9]=c.y; t[10]=c.z; t[11]=c.w;
        }
        #pragma unroll 4
        for (int c = 0; c < DD; ++c) {
            float h = gelu_fast(f_b1[c] + dist * f_w1[c] + vmi * f_w1[DD + c]
                                + vmj * f_w1[2 * DD + c]);
            const float4* wr = (const float4*)(f_w2 + c * DD + 12 * r);
            float4 w0 = wr[0], w1 = wr[1], w2v = wr[2];
            t[0] = fmaf(h, w0.x, t[0]);  t[1] = fmaf(h, w0.y, t[1]);
            t[2] = fmaf(h, w0.z, t[2]);  t[3] = fmaf(h, w0.w, t[3]);
            t[4] = fmaf(h, w1.x, t[4]);  t[5] = fmaf(h, w1.y, t[5]);
            t[6] = fmaf(h, w1.z, t[6]);  t[7] = fmaf(h, w1.w, t[7]);
            t[8] = fmaf(h, w2v.x, t[8]); t[9] = fmaf(h, w2v.y, t[9]);
            t[10] = fmaf(h, w2v.z, t[10]); t[11] = fmaf(h, w2v.w, t[11]);
        }
        float fm;
        {
            const float4* w3p = (const float4*)(f_w3 + 12 * r);
            float4 a = w3p[0], b = w3p[1], c = w3p[2];
            fm  = gelu_fast(t[0]) * a.x + gelu_fast(t[1]) * a.y
                + gelu_fast(t[2]) * a.z + gelu_fast(t[3]) * a.w
                + gelu_fast(t[4]) * b.x + gelu_fast(t[5]) * b.y
                + gelu_fast(t[6]) * b.z + gelu_fast(t[7]) * b.w
                + gelu_fast(t[8]) * c.x + gelu_fast(t[9]) * c.y
                + gelu_fast(t[10]) * c.z + gelu_fast(t[11]) * c.w;
        }
        fm += __shfl_xor(fm, 1);
        fm += __shfl_xor(fm, 2);
        fm += f_b3[0];
        if (r == 0) sFm[el] = fm;
        __syncthreads();
        if (tid < 64) {
            int mjj = tid & 7, mii = (tid >> 3) & 7;
            float v00 = sFm[tid];
            float v01 = (mjj == 7) ? v00 : sFm[tid + 1];
            float v10 = (mii == 7) ? v00 : sFm[tid + 8];
            float v11 = (mii == 7) ? v01 : ((mjj == 7) ? v10 : sFm[tid + 9]);
            // mi=7 / mj=7 entries never dereferenced (massT clamped <= NM-1-eps)
            table4[blockIdx.x * 64 + tid] = make_float4(v00, v01, v10, v11);
        }
    } else {
        int p = (blockIdx.x - 64) * 64 + el;   // 0..2047
        const float4* xp = (const float4*)(pos + (size_t)p * DD + 12 * r);
        float4 x0 = xp[0], x1 = xp[1], x2 = xp[2];
        float xs[12];
        xs[0]=x0.x; xs[1]=x0.y; xs[2]=x0.z; xs[3]=x0.w;
        xs[4]=x1.x; xs[5]=x1.y; xs[6]=x1.z; xs[7]=x1.w;
        xs[8]=x2.x; xs[9]=x2.y; xs[10]=x2.z; xs[11]=x2.w;
        float n2 = 0.f;
        #pragma unroll
        for (int j = 0; j < 12; ++j) n2 = fmaf(xs[j], xs[j], n2);
        n2 += __shfl_xor(n2, 1);
        n2 += __shfl_xor(n2, 2);

        float t[12];
        #pragma unroll
        for (int k = 0; k < 12; ++k) t[k] = 0.f;
        #pragma unroll
        for (int j = 0; j < 12; ++j) {
            const float4* wr = (const float4*)(m_w1 + (size_t)(12 * r + j) * DH);
            float4 a = wr[0], b = wr[1], c = wr[2];
            float xj = xs[j];
            t[0] = fmaf(xj, a.x, t[0]);  t[1] = fmaf(xj, a.y, t[1]);
            t[2] = fmaf(xj, a.z, t[2]);  t[3] = fmaf(xj, a.w, t[3]);
            t[4] = fmaf(xj, b.x, t[4]);  t[5] = fmaf(xj, b.y, t[5]);
            t[6] = fmaf(xj, b.z, t[6]);  t[7] = fmaf(xj, b.w, t[7]);
            t[8] = fmaf(xj, c.x, t[8]);  t[9] = fmaf(xj, c.y, t[9]);
            t[10] = fmaf(xj, c.z, t[10]); t[11] = fmaf(xj, c.w, t[11]);
        }
        #pragma unroll
        for (int k = 0; k < 12; ++k) {
            t[k] += __shfl_xor(t[k], 1);
            t[k] += __shfl_xor(t[k], 2);
        }
        float m2 = m_b2[0];
        #pragma unroll
        for (int k = 0; k < 12; ++k)
            m2 += gelu_exact(t[k] + m_b1[k]) * m_w2[k];
        if (r == 0) {
            float m = softplus_f(m2);
            mass_out[p] = m;
            float mt = fminf(fmaxf((m - M_LO) * MINV, 0.f), (float)(NM - 1) - 1e-3f);
            nm2[p] = make_float2(n2, mt);
        }
    }
}

// ---- one j-column evaluation: dist via norm trick + packed lookup ----
#define CHAIN(PJ0, PJ1, PJ2, NMJ, JIDX, SS, VV0, VV1, VV2)                              \
    {                                                                                    \
        float dp = pi0.x * PJ0.x;                                                        \
        dp = fmaf(pi0.y, PJ0.y, dp); dp = fmaf(pi0.z, PJ0.z, dp);                        \
        dp = fmaf(pi0.w, PJ0.w, dp);                                                     \
        dp = fmaf(pi1.x, PJ1.x, dp); dp = fmaf(pi1.y, PJ1.y, dp);                        \
        dp = fmaf(pi1.z, PJ1.z, dp); dp = fmaf(pi1.w, PJ1.w, dp);                        \
        dp = fmaf(pi2.x, PJ2.x, dp); dp = fmaf(pi2.y, PJ2.y, dp);                        \
        dp = fmaf(pi2.z, PJ2.z, dp); dp = fmaf(pi2.w, PJ2.w, dp);                        \
        dp += __shfl_xor(dp, 1);                                                         \
        dp += __shfl_xor(dp, 2);                                                         \
        float s2 = fmaxf(nmI.x + NMJ.x - 2.f * dp, 0.f);                                 \
        float dist = fmaxf(sqrtf(s2), 0.01f);                                            \
        float td = fminf(fmaxf((dist - D_LO) * DINV, 0.f), (float)(ND - 1) - 1e-3f);     \
        int di0 = (int)td; float fd = td - di0;                                          \
        int nj0 = (int)NMJ.y; float fj = NMJ.y - nj0;                                    \
        int idx = di0 * (NM * NM) + miN + nj0;                                           \
        float4 q0 = table4[idx];                                                         \
        float4 q1 = table4[idx + NM * NM];                                               \
        float a0 = q0.x + fj * (q0.y - q0.x);                                            \
        float a1 = q0.z + fj * (q0.w - q0.z);                                            \
        float y0 = a0 + fi * (a1 - a0);                                                  \
        float b0 = q1.x + fj * (q1.y - q1.x);                                            \
        float b1 = q1.z + fj * (q1.w - q1.z);                                            \
        float y1 = b0 + fi * (b1 - b0);                                                  \
        float fmv = y0 + fd * (y1 - y0);                                                 \
        float rr = ((JIDX) <= gi) ? fmv * __builtin_amdgcn_rcpf(dist) : 0.f;             \
        SS += rr;                                                                        \
        VV0.x = fmaf(rr, PJ0.x, VV0.x); VV0.y = fmaf(rr, PJ0.y, VV0.y);                  \
        VV0.z = fmaf(rr, PJ0.z, VV0.z); VV0.w = fmaf(rr, PJ0.w, VV0.w);                  \
        VV1.x = fmaf(rr, PJ1.x, VV1.x); VV1.y = fmaf(rr, PJ1.y, VV1.y);                  \
        VV1.z = fmaf(rr, PJ1.z, VV1.z); VV1.w = fmaf(rr, PJ1.w, VV1.w);                  \
        VV2.x = fmaf(rr, PJ2.x, VV2.x); VV2.y = fmaf(rr, PJ2.y, VV2.y);                  \
        VV2.z = fmaf(rr, PJ2.z, VV2.z); VV2.w = fmaf(rr, PJ2.w, VV2.w);                  \
    }

// ======== force: 1 wave = (batch, 16-row strip, j-split of 32);
//          4 independent latency chains per loop iteration (stride 128) ========
__global__ __launch_bounds__(256) void force_kernel(
    const float* __restrict__ pos, const float2* __restrict__ nm2,
    const float4* __restrict__ table4, float* __restrict__ partial)
{
    int bid = blockIdx.x;                 // 1024 blocks
    int b = bid & 1;
    int r = bid >> 1;                     // 0..511
    int s = 63 - (r >> 3);                // heavy strips dispatched first
    int g = r & 7;                        // splitgroup -> partial slot
    int tid = threadIdx.x;
    int wid = tid >> 6;
    int lane = tid & 63;
    int li = lane >> 2, q = lane & 3;
    int k = g * 4 + wid;                  // j-split 0..31
    int i0 = s * 16;
    int gi = i0 + li;
    int jmax = i0 + 15;

    const float4* prI = (const float4*)(pos + (size_t)(b * NN + gi) * DD) + 3 * q;
    float4 pi0 = prI[0], pi1 = prI[1], pi2 = prI[2];
    float2 nmI = nm2[b * NN + gi];
    int mi0 = (int)nmI.y; float fi = nmI.y - mi0; int miN = mi0 * NM;

    float SA = 0.f, SB = 0.f;
    float4 VA0 = make_float4(0.f,0.f,0.f,0.f), VA1 = VA0, VA2 = VA0;
    float4 VB0 = VA0, VB1 = VA0, VB2 = VA0;

    for (int j = k; j <= jmax; j += 128) {
        int jB = j + 32, jC = j + 64, jD = j + 96;
        bool hasB = (jB <= jmax), hasC = (jC <= jmax), hasD = (jD <= jmax);
        // issue all loads up front (4 independent chains in flight)
        const float4* sjA = (const float4*)(pos + (size_t)(b * NN + j) * DD) + 3 * q;
        float4 pA0 = sjA[0], pA1 = sjA[1], pA2 = sjA[2];
        float2 nmA = nm2[b * NN + j];
        float4 pB0, pB1, pB2; float2 nmB;
        if (hasB) {
            const float4* sj = (const float4*)(pos + (size_t)(b * NN + jB) * DD) + 3 * q;
            pB0 = sj[0]; pB1 = sj[1]; pB2 = sj[2]; nmB = nm2[b * NN + jB];
        }
        float4 pC0, pC1, pC2; float2 nmC;
        if (hasC) {
            const float4* sj = (const float4*)(pos + (size_t)(b * NN + jC) * DD) + 3 * q;
            pC0 = sj[0]; pC1 = sj[1]; pC2 = sj[2]; nmC = nm2[b * NN + jC];
        }
        float4 pD0, pD1, pD2; float2 nmD;
        if (hasD) {
            const float4* sj = (const float4*)(pos + (size_t)(b * NN + jD) * DD) + 3 * q;
            pD0 = sj[0]; pD1 = sj[1]; pD2 = sj[2]; nmD = nm2[b * NN + jD];
        }

        CHAIN(pA0, pA1, pA2, nmA, j, SA, VA0, VA1, VA2)
        if (hasB) CHAIN(pB0, pB1, pB2, nmB, jB, SB, VB0, VB1, VB2)
        if (hasC) CHAIN(pC0, pC1, pC2, nmC, jC, SA, VA0, VA1, VA2)
        if (hasD) CHAIN(pD0, pD1, pD2, nmD, jD, SB, VB0, VB1, VB2)
    }
    float S = SA + SB;
    float4 V0, V1, V2;
    V0.x = VA0.x + VB0.x; V0.y = VA0.y + VB0.y; V0.z = VA0.z + VB0.z; V0.w = VA0.w + VB0.w;
    V1.x = VA1.x + VB1.x; V1.y = VA1.y + VB1.y; V1.z = VA1.z + VB1.z; V1.w = VA1.w + VB1.w;
    V2.x = VA2.x + VB2.x; V2.y = VA2.y + VB2.y; V2.z = VA2.z + VB2.z; V2.w = VA2.w + VB2.w;

    __shared__ __align__(16) float red[4][16][48];
    float4 f0, f1, f2;
    f0.x = pi0.x * S - V0.x; f0.y = pi0.y * S - V0.y;
    f0.z = pi0.z * S - V0.z; f0.w = pi0.w * S - V0.w;
    f1.x = pi1.x * S - V1.x; f1.y = pi1.y * S - V1.y;
    f1.z = pi1.z * S - V1.z; f1.w = pi1.w * S - V1.w;
    f2.x = pi2.x * S - V2.x; f2.y = pi2.y * S - V2.y;
    f2.z = pi2.z * S - V2.z; f2.w = pi2.w * S - V2.w;
    float4* rp = (float4*)&red[wid][li][12 * q];
    rp[0] = f0; rp[1] = f1; rp[2] = f2;
    __syncthreads();

    if (tid < 192) {
        int i = tid / 12, c4 = tid - (tid / 12) * 12;
        float4 acc = *(const float4*)&red[0][i][4 * c4];
        #pragma unroll
        for (int w = 1; w < 4; ++w) {
            float4 v = *(const float4*)&red[w][i][4 * c4];
            acc.x += v.x; acc.y += v.y; acc.z += v.z; acc.w += v.w;
        }
        ((float4*)partial)[((size_t)(g * BB + b) * NN + i0 + i) * 12 + c4] = acc;
    }
}

// ======== integrate: sum 8 partial slots + update (float4) ========
__global__ void integrate_kernel(const float* __restrict__ pos, const float* __restrict__ vel,
                                 const float* __restrict__ partial, const float* __restrict__ mass,
                                 const float* __restrict__ damping_p, const float* __restrict__ dt_p,
                                 float* __restrict__ out) {
    int e4 = blockIdx.x * blockDim.x + threadIdx.x;
    const int N4 = BB * NN * DD / 4;
    if (e4 >= N4) return;
    int p = e4 / 12;
    float damping = damping_p[0], dt = dt_p[0];
    float inv = 1.0f / (mass[p] + 0.1f);
    float4 f = make_float4(0.f, 0.f, 0.f, 0.f);
    #pragma unroll
    for (int k = 0; k < NSLOT; ++k) {
        float4 pv = ((const float4*)partial)[(size_t)k * N4 + e4];
        f.x += pv.x; f.y += pv.y; f.z += pv.z; f.w += pv.w;
    }
    float4 v = ((const float4*)vel)[e4];
    float4 x = ((const float4*)pos)[e4];
    float4 nv, np;
    nv.x = damping * v.x + dt * (f.x * inv);
    nv.y = damping * v.y + dt * (f.y * inv);
    nv.z = damping * v.z + dt * (f.z * inv);
    nv.w = damping * v.w + dt * (f.w * inv);
    np.x = x.x + dt * nv.x; np.y = x.y + dt * nv.y;
    np.z = x.z + dt * nv.z; np.w = x.w + dt * nv.w;
    ((float4*)out)[e4] = np;
    ((float4*)out)[N4 + e4] = nv;
}

extern "C" void kernel_launch(void* const* d_in, const int* in_sizes, int n_in,
                              void* d_out, int out_size, void* d_ws, size_t ws_size,
                              hipStream_t stream) {
    const float* pos  = (const float*)d_in[0];
    const float* vel  = (const float*)d_in[1];
    const float* m_w1 = (const float*)d_in[2];
    const float* m_b1 = (const float*)d_in[3];
    const float* m_w2 = (const float*)d_in[4];
    const float* m_b2 = (const float*)d_in[5];
    const float* f_w1 = (const float*)d_in[6];
    const float* f_b1 = (const float*)d_in[7];
    const float* f_w2 = (const float*)d_in[8];
    const float* f_b2 = (const float*)d_in[9];
    const float* f_w3 = (const float*)d_in[10];
    const float* f_b3 = (const float*)d_in[11];
    const float* damping = (const float*)d_in[12];
    const float* dt   = (const float*)d_in[13];

    float* partial_ws = (float*)d_ws;                      // NSLOT*98304 floats
    float* mass_ws    = partial_ws + NSLOT * BB * NN * DD; // 2048
    float2* nm2_ws    = (float2*)(mass_ws + BB * NN);      // 2048 float2
    float4* table4_ws = (float4*)(nm2_ws + BB * NN);       // 4096 float4

    prep_kernel<<<96, 256, 0, stream>>>(pos, m_w1, m_b1, m_w2, m_b2,
                                        f_w1, f_b1, f_w2, f_b2, f_w3, f_b3,
                                        mass_ws, nm2_ws, table4_ws);

    force_kernel<<<BB * 64 * NSLOT, 256, 0, stream>>>(pos, nm2_ws, table4_ws, partial_ws);

    integrate_kernel<<<(BB * NN * DD / 4 + 255) / 256, 256, 0, stream>>>(
        pos, vel, partial_ws, mass_ws, damping, dt, (float*)d_out);
}